// Round 7
// baseline (6836.172 us; speedup 1.0000x reference)
//
#include <hip/hip_runtime.h>

#define NN 50000
#define NE 800000

// ---------------- CSR build ----------------
__global__ __launch_bounds__(256) void init_int_kernel(int* __restrict__ a, int n) {
  int i = blockIdx.x * 256 + threadIdx.x;
  if (i < n) a[i] = 0;
}

__global__ __launch_bounds__(256) void hist_kernel(const int* __restrict__ ei,
                                                   int* __restrict__ deg) {
  int e = blockIdx.x * 256 + threadIdx.x;
  if (e < NE) {
    int d = ei[NE + e];
    if ((unsigned)d >= NN) d = 0;
    atomicAdd(&deg[d], 1);
  }
}

__global__ __launch_bounds__(1024) void scan_kernel(const int* __restrict__ deg,
                                                    int* __restrict__ offs) {
  __shared__ int part[1024];
  int tid = threadIdx.x;
  const int chunk = (NN + 1023) / 1024;  // 49
  int base = tid * chunk;
  int s = 0;
  for (int j = 0; j < chunk; ++j) {
    int idx = base + j;
    if (idx < NN) s += deg[idx];
  }
  part[tid] = s;
  __syncthreads();
  for (int off = 1; off < 1024; off <<= 1) {
    int t = (tid >= off) ? part[tid - off] : 0;
    __syncthreads();
    part[tid] += t;
    __syncthreads();
  }
  int run = (tid > 0) ? part[tid - 1] : 0;
  for (int j = 0; j < chunk; ++j) {
    int idx = base + j;
    if (idx < NN) { offs[idx] = run; run += deg[idx]; }
  }
  if (tid == 1023) offs[NN] = part[1023];
}

__global__ __launch_bounds__(256) void scatter_kernel(const int* __restrict__ ei,
    const int* __restrict__ offs, int* __restrict__ cursor,
    int* __restrict__ csr_eid, int* __restrict__ csr_src) {
  int e = blockIdx.x * 256 + threadIdx.x;
  if (e < NE) {
    int s = ei[e];
    int d = ei[NE + e];
    if ((unsigned)s >= NN) s = 0;
    if ((unsigned)d >= NN) d = 0;
    int pos = atomicAdd(&cursor[d], 1);
    int slot = offs[d] + pos;
    csr_eid[slot] = e;
    csr_src[slot] = s;
  }
}

// ---------------- node projections: q(=*0.25), k, v, skipx = x@Wskip+bskip+x ----
__global__ __launch_bounds__(256) void node_proj_kernel(
    const float* __restrict__ x,
    const float* __restrict__ Wq, const float* __restrict__ bq,
    const float* __restrict__ Wk, const float* __restrict__ bk,
    const float* __restrict__ Wv, const float* __restrict__ bv,
    const float* __restrict__ Wsk, const float* __restrict__ bsk,
    float* __restrict__ qo, float* __restrict__ ko, float* __restrict__ vo,
    float* __restrict__ so) {
  __shared__ float xs[64 * 128];
  int tid = threadIdx.x;
  int row0 = blockIdx.x * 64;
  int nrows = NN - row0; if (nrows > 64) nrows = 64;
  const float4* xg = (const float4*)(x + (size_t)row0 * 128);
  float4* xs4 = (float4*)xs;
  int nv = nrows * 32;
  for (int i = tid; i < 64 * 32; i += 256)
    if (i < nv) xs4[i] = xg[i];
  __syncthreads();

  int colg = tid & 31;   // cols colg*4..+3
  int rowg = tid >> 5;   // rows rowg*8..+7
  const float* Wm[4] = {Wq, Wk, Wv, Wsk};
  const float* bm[4] = {bq, bk, bv, bsk};
  float* om[4] = {qo, ko, vo, so};

  for (int m = 0; m < 4; ++m) {
    const float* W = Wm[m];
    float acc[8][4];
    #pragma unroll
    for (int r = 0; r < 8; ++r)
      #pragma unroll
      for (int c = 0; c < 4; ++c) acc[r][c] = 0.f;
    for (int k0 = 0; k0 < 128; k0 += 4) {
      float4 w0 = *(const float4*)(W + (size_t)(k0 + 0) * 128 + colg * 4);
      float4 w1 = *(const float4*)(W + (size_t)(k0 + 1) * 128 + colg * 4);
      float4 w2 = *(const float4*)(W + (size_t)(k0 + 2) * 128 + colg * 4);
      float4 w3 = *(const float4*)(W + (size_t)(k0 + 3) * 128 + colg * 4);
      #pragma unroll
      for (int r = 0; r < 8; ++r) {
        float4 xv = *(const float4*)(&xs[(rowg * 8 + r) * 128 + k0]);
        acc[r][0] += xv.x * w0.x + xv.y * w1.x + xv.z * w2.x + xv.w * w3.x;
        acc[r][1] += xv.x * w0.y + xv.y * w1.y + xv.z * w2.y + xv.w * w3.y;
        acc[r][2] += xv.x * w0.z + xv.y * w1.z + xv.z * w2.z + xv.w * w3.z;
        acc[r][3] += xv.x * w0.w + xv.y * w1.w + xv.z * w2.w + xv.w * w3.w;
      }
    }
    float4 bb = *(const float4*)(bm[m] + colg * 4);
    float* outp = om[m];
    #pragma unroll
    for (int r = 0; r < 8; ++r) {
      int lr = rowg * 8 + r;
      if (lr < nrows) {
        float4 res;
        res.x = acc[r][0] + bb.x;
        res.y = acc[r][1] + bb.y;
        res.z = acc[r][2] + bb.z;
        res.w = acc[r][3] + bb.w;
        if (m == 0) { res.x *= 0.25f; res.y *= 0.25f; res.z *= 0.25f; res.w *= 0.25f; }
        if (m == 3) {
          res.x += xs[lr * 128 + colg * 4 + 0];
          res.y += xs[lr * 128 + colg * 4 + 1];
          res.z += xs[lr * 128 + colg * 4 + 2];
          res.w += xs[lr * 128 + colg * 4 + 3];
        }
        *(float4*)(outp + (size_t)(row0 + lr) * 128 + colg * 4) = res;
      }
    }
  }
}

// ---------------- qe[n,h,j] = sum_c q_scaled[n,h,c] * We[j, h*16+c] ----------
__global__ __launch_bounds__(256) void qe_kernel(const float* __restrict__ q,
                                                 const float* __restrict__ We,
                                                 float* __restrict__ qe) {
  long idx = (long)blockIdx.x * 256 + threadIdx.x;  // N*512 total
  int n = (int)(idx >> 9);
  int r = (int)(idx & 511);
  int h = r >> 6, j = r & 63;
  const float* qp = q + (size_t)n * 128 + h * 16;
  const float* wp = We + (size_t)j * 128 + h * 16;
  float s = 0.f;
  #pragma unroll
  for (int c = 0; c < 16; ++c) s += qp[c] * wp[c];
  qe[idx] = s;
}

// ---------------- per-node attention + LN1 -> hbuf ----------------
__global__ __launch_bounds__(256) void agg_ln1_kernel(
    const float* __restrict__ q, const float* __restrict__ kb,
    const float* __restrict__ vb, const float* __restrict__ qe,
    const float* __restrict__ ea, const float* __restrict__ skipx,
    const float* __restrict__ We,
    const int* __restrict__ offs, const int* __restrict__ csr_eid,
    const int* __restrict__ csr_src,
    const float* __restrict__ g1, const float* __restrict__ b1,
    float* __restrict__ hbuf) {
  __shared__ float ea_s[4][8][68];   // +4 pad breaks bank collisions
  __shared__ float wea_s[4][8][68];
  int tid = threadIdx.x;
  int wave = tid >> 6;
  int lane = tid & 63;
  int node = blockIdx.x * 4 + wave;
  float (*eas)[68] = ea_s[wave];
  float (*weas)[68] = wea_s[wave];

  int g = lane >> 3;
  int hh = lane & 7;

  float q_r[16];
  {
    const float* qp = q + (size_t)node * 128 + hh * 16;
    #pragma unroll
    for (int u = 0; u < 4; ++u) {
      float4 t = *(const float4*)(qp + 4 * u);
      q_r[4*u+0] = t.x; q_r[4*u+1] = t.y; q_r[4*u+2] = t.z; q_r[4*u+3] = t.w;
    }
  }
  float qe_r[64];
  {
    const float* qp = qe + (size_t)node * 512 + hh * 64;
    #pragma unroll
    for (int u = 0; u < 16; ++u) {
      float4 t = *(const float4*)(qp + 4 * u);
      qe_r[4*u+0] = t.x; qe_r[4*u+1] = t.y; qe_r[4*u+2] = t.z; qe_r[4*u+3] = t.w;
    }
  }
  float wea_r[8];
  #pragma unroll
  for (int j = 0; j < 8; ++j) wea_r[j] = 0.f;
  float wv0 = 0.f, wv1 = 0.f, pden = 0.f;

  int base = offs[node];
  int deg = offs[node + 1] - base;

  for (int t0 = 0; t0 < deg; t0 += 8) {
    int myi = t0 + g;
    int valid = myi < deg;
    int slot = base + (valid ? myi : 0);
    int eid = csr_eid[slot];
    int src = csr_src[slot];

    const float4* eap = (const float4*)(ea + (size_t)eid * 64);
    float4 a0 = eap[hh * 2];
    float4 a1 = eap[hh * 2 + 1];
    *(float4*)(&eas[g][hh * 8]) = a0;
    *(float4*)(&eas[g][hh * 8 + 4]) = a1;
    asm volatile("s_waitcnt lgkmcnt(0)" ::: "memory");

    const float* kp = kb + (size_t)src * 128 + hh * 16;
    float lg = 0.f;
    #pragma unroll
    for (int u = 0; u < 4; ++u) {
      float4 kv = *(const float4*)(kp + 4 * u);
      lg += q_r[4*u+0]*kv.x + q_r[4*u+1]*kv.y + q_r[4*u+2]*kv.z + q_r[4*u+3]*kv.w;
    }
    #pragma unroll
    for (int u = 0; u < 16; ++u) {
      float4 av = *(const float4*)(&eas[g][4 * u]);
      lg += qe_r[4*u+0]*av.x + qe_r[4*u+1]*av.y + qe_r[4*u+2]*av.z + qe_r[4*u+3]*av.w;
    }
    float w = valid ? __expf(lg) : 0.f;
    pden += w;

    #pragma unroll
    for (int g2 = 0; g2 < 8; ++g2) {
      int   sg  = __shfl(src, g2 * 8, 64);
      float wgh = __shfl(w, g2 * 8 + g, 64);
      float2 vv = *(const float2*)(vb + (size_t)sg * 128 + lane * 2);
      wv0 += wgh * vv.x;
      wv1 += wgh * vv.y;
      float4 e0 = *(const float4*)(&eas[g2][hh * 8]);
      float4 e1 = *(const float4*)(&eas[g2][hh * 8 + 4]);
      wea_r[0] += wgh * e0.x; wea_r[1] += wgh * e0.y;
      wea_r[2] += wgh * e0.z; wea_r[3] += wgh * e0.w;
      wea_r[4] += wgh * e1.x; wea_r[5] += wgh * e1.y;
      wea_r[6] += wgh * e1.z; wea_r[7] += wgh * e1.w;
    }
    asm volatile("s_waitcnt lgkmcnt(0)" ::: "memory");
  }

  float den = pden;
  den += __shfl_xor(den, 8, 64);
  den += __shfl_xor(den, 16, 64);
  den += __shfl_xor(den, 32, 64);
  float denf = __shfl(den, g, 64);

  *(float4*)(&weas[g][hh * 8])     = make_float4(wea_r[0], wea_r[1], wea_r[2], wea_r[3]);
  *(float4*)(&weas[g][hh * 8 + 4]) = make_float4(wea_r[4], wea_r[5], wea_r[6], wea_r[7]);
  asm volatile("s_waitcnt lgkmcnt(0)" ::: "memory");

  float s0 = wv0, s1 = wv1;
  const float* wep = We + lane * 2;
  #pragma unroll
  for (int u = 0; u < 16; ++u) {
    float4 ww = *(const float4*)(&weas[g][4 * u]);
    float2 p0 = *(const float2*)(wep + (size_t)(4 * u + 0) * 128);
    float2 p1 = *(const float2*)(wep + (size_t)(4 * u + 1) * 128);
    float2 p2 = *(const float2*)(wep + (size_t)(4 * u + 2) * 128);
    float2 p3 = *(const float2*)(wep + (size_t)(4 * u + 3) * 128);
    s0 += ww.x * p0.x + ww.y * p1.x + ww.z * p2.x + ww.w * p3.x;
    s1 += ww.x * p0.y + ww.y * p1.y + ww.z * p2.y + ww.w * p3.y;
  }
  float inv = (deg > 0) ? 1.f / denf : 0.f;
  float2 skv = *(const float2*)(skipx + (size_t)node * 128 + lane * 2);
  float c0 = s0 * inv + skv.x;
  float c1 = s1 * inv + skv.y;

  float sum = c0 + c1;
  float sq = c0 * c0 + c1 * c1;
  #pragma unroll
  for (int o = 1; o < 64; o <<= 1) {
    sum += __shfl_xor(sum, o, 64);
    sq  += __shfl_xor(sq, o, 64);
  }
  float mean = sum * (1.f / 128.f);
  float var = sq * (1.f / 128.f) - mean * mean;
  float rstd = rsqrtf(var + 1e-5f);
  float2 gg = *(const float2*)(g1 + lane * 2);
  float2 bb = *(const float2*)(b1 + lane * 2);
  float h0 = (c0 - mean) * rstd * gg.x + bb.x;
  float h1 = (c1 - mean) * rstd * gg.y + bb.y;
  *(float2*)(hbuf + (size_t)node * 128 + lane * 2) = make_float2(h0, h1);
}

// ---------------- streaming 128x128 GEMM tile with LDS-resident weights ----
// Block: 256 threads. Computes Out[rows 256][cols 128] = act(A[...,K=128] @ W + b)
// W staged TRANSPOSED in LDS (Wlds[c][k], pad 132) -> conflict-bounded b128 reads.
// Thread: 2 rows x 4 cols (cols strided 32 for conflict-free reads + coalesced stores).
__device__ __forceinline__ void tile_gemm_body(
    float* __restrict__ Wlds, float* __restrict__ hls,
    const float* __restrict__ A, int lda, int kofs,
    const float* __restrict__ W, int ldw, int kw0, int c0w,
    const float* __restrict__ bias,  // pre-offset to col base; nullptr -> 0
    bool do_gelu,
    float* __restrict__ Out, int ldo, int c0o, int row0) {
  int tid = threadIdx.x;
  // stage W transposed: Wlds[c*132 + k] = W[(kw0+k)*ldw + c0w + c]
  for (int i = tid; i < 128 * 32; i += 256) {
    int k = i >> 5, cq = i & 31;
    float4 w = *(const float4*)(W + (size_t)(kw0 + k) * ldw + c0w + cq * 4);
    Wlds[(cq * 4 + 0) * 132 + k] = w.x;
    Wlds[(cq * 4 + 1) * 132 + k] = w.y;
    Wlds[(cq * 4 + 2) * 132 + k] = w.z;
    Wlds[(cq * 4 + 3) * 132 + k] = w.w;
  }
  int c4 = tid & 31;
  int rp = tid >> 5;  // 0..7
  float bj[4];
  #pragma unroll
  for (int j = 0; j < 4; ++j) bj[j] = bias ? bias[c4 + 32 * j] : 0.f;
  __syncthreads();

  int rows_blk = NN - row0; if (rows_blk > 256) rows_blk = 256;
  int nbat = (rows_blk + 15) >> 4;
  for (int b = 0; b < nbat; ++b) {
    int rb0 = row0 + b * 16;
    // stage 16 A-rows (512 float4, 2 per thread), zero-pad OOB
    for (int i = tid; i < 512; i += 256) {
      int r = i >> 5, qq = i & 31;
      int gr = rb0 + r;
      float4 v = make_float4(0.f, 0.f, 0.f, 0.f);
      if (gr < NN) v = *(const float4*)(A + (size_t)gr * lda + kofs + qq * 4);
      *(float4*)(hls + r * 128 + qq * 4) = v;
    }
    __syncthreads();

    float acc0[4], acc1[4];
    #pragma unroll
    for (int j = 0; j < 4; ++j) { acc0[j] = bj[j]; acc1[j] = bj[j]; }
    int r0 = rp * 2, r1 = rp * 2 + 1;
    #pragma unroll
    for (int k0 = 0; k0 < 128; k0 += 4) {
      float4 h0 = *(const float4*)(hls + r0 * 128 + k0);
      float4 h1 = *(const float4*)(hls + r1 * 128 + k0);
      #pragma unroll
      for (int j = 0; j < 4; ++j) {
        float4 wv = *(const float4*)(Wlds + (c4 + 32 * j) * 132 + k0);
        acc0[j] += h0.x * wv.x + h0.y * wv.y + h0.z * wv.z + h0.w * wv.w;
        acc1[j] += h1.x * wv.x + h1.y * wv.y + h1.z * wv.z + h1.w * wv.w;
      }
    }

    int gr0 = rb0 + r0, gr1 = rb0 + r1;
    #pragma unroll
    for (int j = 0; j < 4; ++j) {
      float v0 = acc0[j], v1 = acc1[j];
      if (do_gelu) {
        v0 = 0.5f * v0 * (1.f + erff(v0 * 0.70710678118654752440f));
        v1 = 0.5f * v1 * (1.f + erff(v1 * 0.70710678118654752440f));
      }
      int col = c0o + c4 + 32 * j;
      if (gr0 < NN) Out[(size_t)gr0 * ldo + col] = v0;
      if (gr1 < NN) Out[(size_t)gr1 * ldo + col] = v1;
    }
    __syncthreads();  // hls reuse guard
  }
}

// ffn1: t[N][512] = gelu(h @ Wf1 + bf1); grid (196, 4), t aliases qeb
__global__ __launch_bounds__(256) void ffn1_kernel(
    const float* __restrict__ hbuf, const float* __restrict__ Wf1,
    const float* __restrict__ bf1, float* __restrict__ t) {
  __shared__ float Wlds[128 * 132];
  __shared__ float hls[16 * 128];
  int ti = blockIdx.y;
  tile_gemm_body(Wlds, hls,
                 hbuf, 128, 0,
                 Wf1, 512, 0, ti * 128,
                 bf1 + ti * 128, true,
                 t, 512, ti * 128, blockIdx.x * 256);
}

// ffn2a: P_kt[N][128] = t[:, kt*128..+128] @ Wf2[kt*128..+128, :]; grid (196, 4)
__global__ __launch_bounds__(256) void ffn2a_kernel(
    const float* __restrict__ t, const float* __restrict__ Wf2,
    float* __restrict__ p0, float* __restrict__ p1,
    float* __restrict__ p2, float* __restrict__ p3) {
  __shared__ float Wlds[128 * 132];
  __shared__ float hls[16 * 128];
  int kt = blockIdx.y;
  float* P = (kt == 0) ? p0 : (kt == 1) ? p1 : (kt == 2) ? p2 : p3;
  tile_gemm_body(Wlds, hls,
                 t, 512, kt * 128,
                 Wf2, 128, kt * 128, 0,
                 nullptr, false,
                 P, 128, 0, blockIdx.x * 256);
}

// ffn2b: out = LN2(P0+P1+P2+P3 + bf2 + hbuf); P3 lives in `out`. grid 12500.
__global__ __launch_bounds__(256) void ffn2b_kernel(
    const float* __restrict__ p0, const float* __restrict__ p1,
    const float* __restrict__ p2, const float* __restrict__ hbuf,
    const float* __restrict__ bf2,
    const float* __restrict__ g2v, const float* __restrict__ b2v,
    float* __restrict__ out) {
  int tid = threadIdx.x;
  int lane = tid & 63;
  int node = blockIdx.x * 4 + (tid >> 6);
  size_t base = (size_t)node * 128 + lane * 2;
  float2 a0 = *(const float2*)(p0 + base);
  float2 a1 = *(const float2*)(p1 + base);
  float2 a2 = *(const float2*)(p2 + base);
  float2 a3 = *(const float2*)(out + base);   // P3
  float2 hh = *(const float2*)(hbuf + base);
  float2 bb = *(const float2*)(bf2 + lane * 2);
  float c0 = a0.x + a1.x + a2.x + a3.x + bb.x + hh.x;
  float c1 = a0.y + a1.y + a2.y + a3.y + bb.y + hh.y;

  float sum = c0 + c1;
  float sq = c0 * c0 + c1 * c1;
  #pragma unroll
  for (int o = 1; o < 64; o <<= 1) {
    sum += __shfl_xor(sum, o, 64);
    sq  += __shfl_xor(sq, o, 64);
  }
  float mean = sum * (1.f / 128.f);
  float var = sq * (1.f / 128.f) - mean * mean;
  float rstd = rsqrtf(var + 1e-5f);
  float2 gg = *(const float2*)(g2v + lane * 2);
  float2 b2 = *(const float2*)(b2v + lane * 2);
  float o0 = (c0 - mean) * rstd * gg.x + b2.x;
  float o1 = (c1 - mean) * rstd * gg.y + b2.y;
  *(float2*)(out + base) = make_float2(o0, o1);
}

extern "C" void kernel_launch(void* const* d_in, const int* in_sizes, int n_in,
                              void* d_out, int out_size, void* d_ws, size_t ws_size,
                              hipStream_t stream) {
  const float* x   = (const float*)d_in[0];
  const int* ei    = (const int*)d_in[1];
  const float* ea  = (const float*)d_in[2];
  const float* Wq  = (const float*)d_in[3];  const float* bq  = (const float*)d_in[4];
  const float* Wk  = (const float*)d_in[5];  const float* bk  = (const float*)d_in[6];
  const float* Wv  = (const float*)d_in[7];  const float* bv  = (const float*)d_in[8];
  const float* We  = (const float*)d_in[9];
  const float* Wsk = (const float*)d_in[10]; const float* bsk = (const float*)d_in[11];
  const float* g1  = (const float*)d_in[12]; const float* b1  = (const float*)d_in[13];
  const float* g2  = (const float*)d_in[14]; const float* b2  = (const float*)d_in[15];
  const float* Wf1 = (const float*)d_in[16]; const float* bf1 = (const float*)d_in[17];
  const float* Wf2 = (const float*)d_in[18]; const float* bf2 = (const float*)d_in[19];
  float* outp = (float*)d_out;

  char* w = (char*)d_ws;
  float* qb   = (float*)w; w += (size_t)NN * 128 * 4;
  float* kb   = (float*)w; w += (size_t)NN * 128 * 4;
  float* vb   = (float*)w; w += (size_t)NN * 128 * 4;
  float* sk   = (float*)w; w += (size_t)NN * 128 * 4;
  float* hb   = sk;  // alias: agg_ln1 reads skipx[node] before writing hbuf[node]
  float* qeb  = (float*)w; w += (size_t)NN * 512 * 4;   // later reused as FFN t-buffer
  int* deg    = (int*)w;   w += (size_t)NN * 4;
  int* cursor = (int*)w;   w += (size_t)NN * 4;
  int* offs   = (int*)w;   w += (size_t)(NN + 1) * 4;
  int* ceid   = (int*)w;   w += (size_t)NE * 4;
  int* csrc   = (int*)w;   w += (size_t)NE * 4;

  init_int_kernel<<<(2 * NN + 255) / 256, 256, 0, stream>>>(deg, 2 * NN);
  hist_kernel<<<NE / 256, 256, 0, stream>>>(ei, deg);
  scan_kernel<<<1, 1024, 0, stream>>>(deg, offs);
  scatter_kernel<<<NE / 256, 256, 0, stream>>>(ei, offs, cursor, ceid, csrc);
  node_proj_kernel<<<(NN + 63) / 64, 256, 0, stream>>>(x, Wq, bq, Wk, bk, Wv, bv, Wsk, bsk,
                                                       qb, kb, vb, sk);
  qe_kernel<<<NN * 2, 256, 0, stream>>>(qb, We, qeb);
  agg_ln1_kernel<<<NN / 4, 256, 0, stream>>>(qb, kb, vb, qeb, ea, sk, We,
                                             offs, ceid, csrc, g1, b1, hb);
  // FFN: streaming GEMMs with LDS-resident weights.
  // t aliases qeb (dead after agg_ln1); partials alias qb/kb/vb (dead) + d_out.
  dim3 g196x4(196, 4);
  ffn1_kernel<<<g196x4, 256, 0, stream>>>(hb, Wf1, bf1, qeb);
  ffn2a_kernel<<<g196x4, 256, 0, stream>>>(qeb, Wf2, qb, kb, vb, outp);
  ffn2b_kernel<<<NN / 4, 256, 0, stream>>>(qb, kb, vb, hb, bf2, g2, b2, outp);
}